// Round 13
// baseline (228.043 us; speedup 1.0000x reference)
//
#include <hip/hip_runtime.h>

typedef __attribute__((ext_vector_type(8))) short bf16x8;
typedef __attribute__((ext_vector_type(4))) float f32x4;

constexpr int NB = 16;    // bases
constexpr int REFF = 9;   // relations

struct alignas(8) EPair { float v; int c; };   // c = src | (dst&31)<<20

__device__ __forceinline__ unsigned short f2bf(float f) {
  unsigned u = __float_as_uint(f);
  u += 0x7FFFu + ((u >> 16) & 1u);          // round-to-nearest-even
  return (unsigned short)(u >> 16);
}
__device__ __forceinline__ float bflo(unsigned u) {
  return __uint_as_float(u << 16);
}
__device__ __forceinline__ float bfhi(unsigned u) {
  return __uint_as_float(u & 0xFFFF0000u);
}
// bijective within each 512B stripe; spreads rows and the two 16-row halves
__device__ __forceinline__ int swz(int row) {
  return ((row & 7) << 4) ^ ((row & 16) << 1);
}

// ---------------- merged: histogram + prep (Xbf, W1p, W2p) ----------------
__device__ __forceinline__ unsigned short pack_w_one(const float* __restrict__ comps,
                                                     const float* __restrict__ bases,
                                                     int idx, int NTI, int NTOT) {
  int j = idx & 7;
  int lane = (idx >> 3) & 63;
  int ni = (idx >> 9) % NTI;
  int t = (idx >> 9) / NTI;        // r*8 + ks
  int ks = t & 7;
  int r = t >> 3;
  int k = ks * 32 + ((lane >> 4) << 3) + j;
  int n = ni * 16 + (lane & 15);
  float acc = 0.f;
#pragma unroll
  for (int b = 0; b < NB; ++b)
    acc += comps[r * NB + b] * bases[(size_t)b * 256 * NTOT + (size_t)k * NTOT + n];
  return f2bf(acc);
}

__global__ void hist_prep_kernel(const int* __restrict__ rows,
                                 int* __restrict__ deg1, int E,
                                 const float* __restrict__ features,
                                 unsigned short* __restrict__ Xbf,
                                 const float* __restrict__ comps1,
                                 const float* __restrict__ bases1,
                                 unsigned short* __restrict__ W1p,
                                 const float* __restrict__ comps2,
                                 const float* __restrict__ bases2,
                                 unsigned short* __restrict__ W2p, int N) {
  int idx = blockIdx.x * 256 + threadIdx.x;
  if (idx < E) atomicAdd(&deg1[rows[idx]], 1);
  const int n4 = N * 64;                 // float4 units of features
  const int PW1 = REFF * 8 * 16 * 512;   // 589824
  const int PW2 = REFF * 8 * 2 * 512;    // 73728
  if (idx < n4) {
    float4 f = reinterpret_cast<const float4*>(features)[idx];
    ushort4 o;
    o.x = f2bf(f.x); o.y = f2bf(f.y); o.z = f2bf(f.z); o.w = f2bf(f.w);
    reinterpret_cast<ushort4*>(Xbf)[idx] = o;
  } else if (idx < n4 + PW1) {
    int i = idx - n4;
    W1p[i] = pack_w_one(comps1, bases1, i, 16, 256);
  } else if (idx < n4 + PW1 + PW2) {
    int i = idx - n4 - PW1;
    W2p[i] = pack_w_one(comps2, bases2, i, 2, 32);
  }
}

// ---------------- scan over NR rows (R3-proven 3-pass) ----------------
__global__ void scan1_kernel(const int* __restrict__ deg, int* __restrict__ bsum,
                             int NR) {
  __shared__ int s[256];
  int t = threadIdx.x;
  int base = blockIdx.x * 1024 + t * 4;
  int acc = 0;
#pragma unroll
  for (int q = 0; q < 4; ++q)
    if (base + q < NR) acc += deg[base + q];
  s[t] = acc;
  __syncthreads();
  for (int off = 128; off > 0; off >>= 1) {
    if (t < off) s[t] += s[t + off];
    __syncthreads();
  }
  if (t == 0) bsum[blockIdx.x] = s[0];
}

__global__ void scan2_kernel(int* __restrict__ bsum, int* __restrict__ ptr,
                             int NT, int NR) {
  __shared__ int s[512];
  int t = threadIdx.x;
  int v = (t < NT) ? bsum[t] : 0;
  s[t] = v;
  __syncthreads();
  for (int off = 1; off < 512; off <<= 1) {
    int x = (t >= off) ? s[t - off] : 0;
    __syncthreads();
    s[t] += x;
    __syncthreads();
  }
  if (t < NT) bsum[t] = s[t] - v;          // exclusive
  if (t == NT - 1) ptr[NR] = s[t];
}

__global__ void scan3_kernel(const int* __restrict__ deg,
                             const int* __restrict__ bsum,
                             int* __restrict__ ptr, int NR) {
  __shared__ int s[256];
  int t = threadIdx.x;
  int base = blockIdx.x * 1024 + t * 4;
  int d[4];
#pragma unroll
  for (int q = 0; q < 4; ++q)
    d[q] = (base + q < NR) ? deg[base + q] : 0;
  int tsum = d[0] + d[1] + d[2] + d[3];
  s[t] = tsum;
  __syncthreads();
  for (int off = 1; off < 256; off <<= 1) {
    int x = (t >= off) ? s[t - off] : 0;
    __syncthreads();
    s[t] += x;
    __syncthreads();
  }
  int off0 = bsum[blockIdx.x] + s[t] - tsum;
#pragma unroll
  for (int q = 0; q < 4; ++q) {
    if (base + q < NR) ptr[base + q] = off0;
    off0 += d[q];
  }
}

__global__ void fill_kernel(const int* __restrict__ rows,
                            const int* __restrict__ cols,
                            const float* __restrict__ vals,
                            int* __restrict__ deg1, const int* __restrict__ ptr1,
                            EPair* __restrict__ pay1, int E, int N) {
  int e = blockIdx.x * 256 + threadIdx.x;
  if (e >= E) return;
  int g = rows[e];
  int dst = g % N;
  int o1 = atomicSub(&deg1[g], 1);
  EPair pv; pv.v = vals[e]; pv.c = cols[e] | ((dst & 31) << 20);
  pay1[ptr1[g] + o1 - 1] = pv;
}

// ---------------- fused layer 1: barrier-free wave-private MFMA aggregation ----------------
// 512 threads / 8 waves; 32-node tile. Wave w owns features n in [w*32, w*32+32).
// Per chunk (32 edges): wave stages its Xw[32 n'][32 k] + Mw[32 node][32 k] privately,
// 4 MFMAs accumulate aggT; NO block barriers inside the chunk loop.
__global__ __launch_bounds__(512, 4)
void fused_l1(const EPair* __restrict__ pay1, const int* __restrict__ ptr1,
              const unsigned short* __restrict__ Xbf,
              const unsigned short* __restrict__ W1p,
              const float* __restrict__ bias1,
              const unsigned short* __restrict__ W2p,
              unsigned short* __restrict__ Y2, int N) {
  __shared__ char smem[48 * 1024];
  const int tid = threadIdx.x;
  const int w = tid >> 6, lane = tid & 63;
  const int l15 = lane & 15, kg = lane >> 4;
  char* Xw   = smem + w * 2048;             // wave-private [32 n'][32 k] bf16, swizzled
  char* Mw   = smem + 16 * 1024 + w * 2048; // wave-private [32 node][32 k] bf16, swizzled
  char* tile = smem + 32 * 1024;            // shared 16 KB [32 node][256 n] (W1 A-layout)

  const int node0 = blockIdx.x * 32;
  const int nrows = (N - node0 < 32) ? (N - node0) : 32;
  const int e = lane & 31, h = lane >> 5;   // edge slot / n-half within wave slice

  // zero own Xw (thread t covers bytes [t*32, t*32+32) -> wave-aligned)
  {
    uint4 z = make_uint4(0, 0, 0, 0);
    *reinterpret_cast<uint4*>(smem + tid * 32) = z;
    *reinterpret_cast<uint4*>(smem + tid * 32 + 16) = z;
  }

  f32x4 acc[2][2];
#pragma unroll
  for (int mi = 0; mi < 2; ++mi)
#pragma unroll
    for (int ni = 0; ni < 2; ++ni) acc[mi][ni] = (f32x4)(0.f);

  // prologue: prefetch chunk 0 of r=0
  int s0 = ptr1[node0], s1 = ptr1[node0 + nrows];
  EPair pe; bf16x8 px0, px1;
  {
    int rem = s1 - s0; if (rem > 32) rem = 32;
    if (e < rem) {
      pe = pay1[s0 + e];
      const unsigned short* xr = Xbf + (size_t)(pe.c & 0xFFFFF) * 256 + w * 32 + h * 16;
      px0 = *reinterpret_cast<const bf16x8*>(xr);
      px1 = *reinterpret_cast<const bf16x8*>(xr + 8);
    }
  }

  for (int r = 0; r < REFF; ++r) {
    int nch = (s1 - s0 + 31) >> 5;
    f32x4 agg[2][2];
#pragma unroll
    for (int mi = 0; mi < 2; ++mi)
#pragma unroll
      for (int ni = 0; ni < 2; ++ni) agg[mi][ni] = (f32x4)(0.f);

    for (int c = 0; c < nch; ++c) {
      int rem = s1 - (s0 + c * 32); if (rem > 32) rem = 32;
      // publish chunk c from regs: 16 transposed 2B stores into Xw
      if (e < rem) {
#pragma unroll
        for (int i = 0; i < 8; ++i) {
          int np = h * 16 + i;
          *reinterpret_cast<unsigned short*>(Xw + ((np * 64 + e * 2) ^ swz(np))) =
              (unsigned short)px0[i];
        }
#pragma unroll
        for (int i = 0; i < 8; ++i) {
          int np = h * 16 + 8 + i;
          *reinterpret_cast<unsigned short*>(Xw + ((np * 64 + e * 2) ^ swz(np))) =
              (unsigned short)px1[i];
        }
      }
      // Mw: zero (2 KB by own wave) then scatter coefficients (lanes 0..31)
      {
        uint4 z = make_uint4(0, 0, 0, 0);
        *reinterpret_cast<uint4*>(Mw + lane * 32) = z;
        *reinterpret_cast<uint4*>(Mw + lane * 32 + 16) = z;
      }
      if (h == 0 && e < rem) {
        int rr = (pe.c >> 20) & 31;
        *reinterpret_cast<unsigned short*>(Mw + ((rr * 64 + e * 2) ^ swz(rr))) =
            f2bf(pe.v);
      }
      // prefetch chunk c+1 (latency hides under MFMA + next publish; no barriers)
      if (c + 1 < nch) {
        int remn = s1 - (s0 + (c + 1) * 32); if (remn > 32) remn = 32;
        if (e < remn) {
          pe = pay1[s0 + (c + 1) * 32 + e];
          const unsigned short* xr = Xbf + (size_t)(pe.c & 0xFFFFF) * 256 + w * 32 + h * 16;
          px0 = *reinterpret_cast<const bf16x8*>(xr);
          px1 = *reinterpret_cast<const bf16x8*>(xr + 8);
        }
      }
      // aggT += Xw @ Mw  (same-wave LDS deps; compiler inserts lgkmcnt waits)
      {
        bf16x8 a0 = *reinterpret_cast<const bf16x8*>(
            Xw + ((l15 * 64 + kg * 16) ^ swz(l15)));
        bf16x8 a1 = *reinterpret_cast<const bf16x8*>(
            Xw + (((l15 + 16) * 64 + kg * 16) ^ swz(l15 + 16)));
        bf16x8 b0 = *reinterpret_cast<const bf16x8*>(
            Mw + ((l15 * 64 + kg * 16) ^ swz(l15)));
        bf16x8 b1 = *reinterpret_cast<const bf16x8*>(
            Mw + (((l15 + 16) * 64 + kg * 16) ^ swz(l15 + 16)));
        agg[0][0] = __builtin_amdgcn_mfma_f32_16x16x32_bf16(a0, b0, agg[0][0], 0, 0, 0);
        agg[0][1] = __builtin_amdgcn_mfma_f32_16x16x32_bf16(a0, b1, agg[0][1], 0, 0, 0);
        agg[1][0] = __builtin_amdgcn_mfma_f32_16x16x32_bf16(a1, b0, agg[1][0], 0, 0, 0);
        agg[1][1] = __builtin_amdgcn_mfma_f32_16x16x32_bf16(a1, b1, agg[1][1], 0, 0, 0);
      }
    }

    // write aggT -> shared tile[node][n] (bf16, swizzled W1 A-layout)
#pragma unroll
    for (int mi = 0; mi < 2; ++mi)
#pragma unroll
      for (int nj = 0; nj < 2; ++nj)
#pragma unroll
        for (int reg = 0; reg < 4; ++reg) {
          int node = nj * 16 + l15;
          int n = w * 32 + mi * 16 + kg * 4 + reg;
          int byte = (node * 512 + n * 2) ^ ((node & 7) << 4);
          *reinterpret_cast<unsigned short*>(tile + byte) = f2bf(agg[mi][nj][reg]);
        }
    __syncthreads();

    // prefetch r+1's first chunk under the W1 phase
    if (r + 1 < REFF) {
      s0 = ptr1[(r + 1) * N + node0];
      s1 = ptr1[(r + 1) * N + node0 + nrows];
      int rem = s1 - s0; if (rem > 32) rem = 32;
      if (e < rem) {
        pe = pay1[s0 + e];
        const unsigned short* xr = Xbf + (size_t)(pe.c & 0xFFFFF) * 256 + w * 32 + h * 16;
        px0 = *reinterpret_cast<const bf16x8*>(xr);
        px1 = *reinterpret_cast<const bf16x8*>(xr + 8);
      }
    }

    // acc += tile @ W1_r
#pragma unroll 2
    for (int ks = 0; ks < 8; ++ks) {
      bf16x8 a[2];
#pragma unroll
      for (int mi = 0; mi < 2; ++mi) {
        int row = mi * 16 + l15;
        int boff = (row * 512 + ks * 64 + (kg << 4)) ^ ((row & 7) << 4);
        a[mi] = *reinterpret_cast<const bf16x8*>(tile + boff);
      }
#pragma unroll
      for (int ni = 0; ni < 2; ++ni) {
        int niG = w * 2 + ni;
        bf16x8 b = *reinterpret_cast<const bf16x8*>(
            W1p + (((size_t)(r * 8 + ks) * 16 + niG) << 9) + lane * 8);
#pragma unroll
        for (int mi = 0; mi < 2; ++mi)
          acc[mi][ni] = __builtin_amdgcn_mfma_f32_16x16x32_bf16(a[mi], b,
                                                               acc[mi][ni], 0, 0, 0);
      }
    }
    __syncthreads();
  }

  // epilogue: out1 tile = bf16(relu(acc + bias1)) -> tile (same layout)
#pragma unroll
  for (int mi = 0; mi < 2; ++mi) {
#pragma unroll
    for (int ni = 0; ni < 2; ++ni) {
      int col = (w * 2 + ni) * 16 + l15;
      float bb = bias1[col];
#pragma unroll
      for (int reg = 0; reg < 4; ++reg) {
        int row = mi * 16 + (kg << 2) + reg;
        float v = fmaxf(acc[mi][ni][reg] + bb, 0.f);
        int b = (row * 512 + col * 2) ^ ((row & 7) << 4);
        *reinterpret_cast<unsigned short*>(tile + b) = f2bf(v);
      }
    }
  }
  __syncthreads();

  // layer-2 transform: wave w handles rp = w (wave 0 also rp=8); staged stores
  unsigned short* ys = reinterpret_cast<unsigned short*>(Xw);  // 2 KB wave-private
  for (int rp = w; rp < REFF; rp += 8) {
    f32x4 a2[2][2];   // [mi][nj]
#pragma unroll
    for (int mi = 0; mi < 2; ++mi) {
      a2[mi][0] = (f32x4)(0.f);
      a2[mi][1] = (f32x4)(0.f);
    }
#pragma unroll
    for (int ks = 0; ks < 8; ++ks) {
      bf16x8 b0 = *reinterpret_cast<const bf16x8*>(
          W2p + (((size_t)(rp * 8 + ks) * 2 + 0) << 9) + lane * 8);
      bf16x8 b1 = *reinterpret_cast<const bf16x8*>(
          W2p + (((size_t)(rp * 8 + ks) * 2 + 1) << 9) + lane * 8);
#pragma unroll
      for (int mi = 0; mi < 2; ++mi) {
        int row = mi * 16 + l15;
        int boff = (row * 512 + ks * 64 + (kg << 4)) ^ ((row & 7) << 4);
        bf16x8 a = *reinterpret_cast<const bf16x8*>(tile + boff);
        a2[mi][0] = __builtin_amdgcn_mfma_f32_16x16x32_bf16(a, b0, a2[mi][0], 0, 0, 0);
        a2[mi][1] = __builtin_amdgcn_mfma_f32_16x16x32_bf16(a, b1, a2[mi][1], 0, 0, 0);
      }
    }
    // stage 32x32 bf16 into wave-private LDS, then full-line stores
#pragma unroll
    for (int mi = 0; mi < 2; ++mi)
#pragma unroll
      for (int reg = 0; reg < 4; ++reg) {
        int row16 = mi * 16 + (kg << 2) + reg;
        ys[row16 * 32 + l15] = f2bf(a2[mi][0][reg]);
        ys[row16 * 32 + 16 + l15] = f2bf(a2[mi][1][reg]);
      }
    asm volatile("s_waitcnt lgkmcnt(0)" ::: "memory");
#pragma unroll
    for (int half = 0; half < 2; ++half) {
      int row = half * 16 + (lane >> 2);      // 0..31
      int chunk = lane & 3;                   // 16B chunk within 64B row slice
      uint4 v = *reinterpret_cast<const uint4*>(&ys[row * 32 + chunk * 8]);
      int grow = node0 + row;
      if (grow < N)
        *reinterpret_cast<uint4*>(Y2 + (size_t)grow * (REFF * 32) + rp * 32 + chunk * 8) = v;
    }
  }
}

// ---------------- layer 2 gather off CSR1: out[n] = bias2 + sum_r sum_e v*Y2[src][r] ----------------
__global__ __launch_bounds__(512, 8)
void gather_out_kernel(const EPair* __restrict__ pay1,
                       const int* __restrict__ ptr1,
                       const unsigned short* __restrict__ Y2,
                       const float* __restrict__ bias2,
                       float* __restrict__ out, int N) {
  int wv = threadIdx.x >> 6;
  int lane = threadIdx.x & 63;
  int qw = lane >> 4, c = lane & 15;
  int n = blockIdx.x * 8 + wv;
  if (n >= N) return;
  float ax = 0.f, ay = 0.f;
  for (int r = qw; r < REFF; r += 4) {
    int g = r * N + n;
    int p0 = ptr1[g], p1 = ptr1[g + 1];
    int p = p0;
    for (; p + 2 <= p1; p += 2) {
      EPair e0 = pay1[p];
      EPair e1 = pay1[p + 1];
      unsigned u0 = *reinterpret_cast<const unsigned*>(
          Y2 + (size_t)(e0.c & 0xFFFFF) * (REFF * 32) + r * 32 + c * 2);
      unsigned u1 = *reinterpret_cast<const unsigned*>(
          Y2 + (size_t)(e1.c & 0xFFFFF) * (REFF * 32) + r * 32 + c * 2);
      ax += e0.v * bflo(u0) + e1.v * bflo(u1);
      ay += e0.v * bfhi(u0) + e1.v * bfhi(u1);
    }
    if (p < p1) {
      EPair e0 = pay1[p];
      unsigned u0 = *reinterpret_cast<const unsigned*>(
          Y2 + (size_t)(e0.c & 0xFFFFF) * (REFF * 32) + r * 32 + c * 2);
      ax += e0.v * bflo(u0);
      ay += e0.v * bfhi(u0);
    }
  }
  ax += __shfl_xor(ax, 16); ay += __shfl_xor(ay, 16);
  ax += __shfl_xor(ax, 32); ay += __shfl_xor(ay, 32);
  if (lane < 16) {
    float2 o;
    o.x = ax + bias2[c * 2];
    o.y = ay + bias2[c * 2 + 1];
    reinterpret_cast<float2*>(out)[(size_t)n * 16 + c] = o;
  }
}

extern "C" void kernel_launch(void* const* d_in, const int* in_sizes, int n_in,
                              void* d_out, int out_size, void* d_ws, size_t ws_size,
                              hipStream_t stream) {
  const float* features = (const float*)d_in[0];
  const float* ver_vals = (const float*)d_in[1];
  const float* comps1   = (const float*)d_in[2];
  const float* bases1   = (const float*)d_in[3];
  const float* comps2   = (const float*)d_in[4];
  const float* bases2   = (const float*)d_in[5];
  const float* bias1    = (const float*)d_in[6];
  const float* bias2    = (const float*)d_in[7];
  const int* ver_rows   = (const int*)d_in[8];
  const int* ver_cols   = (const int*)d_in[9];

  const int N = in_sizes[0] / 256;   // 30000
  const int E = in_sizes[1];         // 500000
  const int NR = REFF * N;           // 270000
  const int NT = (NR + 1023) / 1024; // 264

  // ---- workspace layout (~40 MB; 64.1 MB proven-safe) ----
  char* p = (char*)d_ws;
  unsigned short* Xbf = (unsigned short*)p; p += (size_t)N * 256 * 2;        // 15.36 MB
  unsigned short* Y2  = (unsigned short*)p; p += (size_t)N * REFF * 32 * 2;  // 17.28 MB
  unsigned short* W1p = (unsigned short*)p; p += (size_t)REFF * 65536 * 2;   // 1.18 MB
  unsigned short* W2p = (unsigned short*)p; p += (size_t)REFF * 8192 * 2;    // 0.15 MB
  int* ptr1 = (int*)p;     p += (size_t)(NR + 4) * 4;
  EPair* pay1 = (EPair*)p; p += (size_t)E * 8;
  int* deg1 = (int*)p;     p += (size_t)NR * 4;
  int* bsum = (int*)p;     p += 512 * 4;

  // ---- CSR build + prep ----
  hipMemsetAsync(deg1, 0, (size_t)NR * 4, stream);
  const int prep_total = N * 64 + REFF * 8 * 16 * 512 + REFF * 8 * 2 * 512;
  const int hp_grid = ((prep_total > E ? prep_total : E) + 255) / 256;
  hist_prep_kernel<<<hp_grid, 256, 0, stream>>>(ver_rows, deg1, E,
                                                features, Xbf,
                                                comps1, bases1, W1p,
                                                comps2, bases2, W2p, N);
  scan1_kernel<<<NT, 256, 0, stream>>>(deg1, bsum, NR);
  scan2_kernel<<<1, 512, 0, stream>>>(bsum, ptr1, NT, NR);
  scan3_kernel<<<NT, 256, 0, stream>>>(deg1, bsum, ptr1, NR);
  fill_kernel<<<(E + 255) / 256, 256, 0, stream>>>(ver_rows, ver_cols, ver_vals,
                                                   deg1, ptr1, pay1, E, N);

  // ---- fused layer 1 (barrier-free MFMA aggregation) + layer-2 transform ----
  fused_l1<<<(N + 31) / 32, 512, 0, stream>>>(pay1, ptr1, Xbf, W1p, bias1,
                                              W2p, Y2, N);
  // ---- layer 2 gather ----
  gather_out_kernel<<<(N + 7) / 8, 512, 0, stream>>>(pay1, ptr1, Y2, bias2,
                                                     (float*)d_out, N);
}